// Round 4
// baseline (2129.840 us; speedup 1.0000x reference)
//
#include <hip/hip_runtime.h>

// Padded layout for all intermediates: [N][C][30][32] floats.
// Row 0 / row 29 are y-halos; col 0 / col 29 are x-halos (zero); cols 30,31 pad.
// Element (y,x) of the logical 28x28 image lives at [y+1][x+1].
#define PADH 30
#define PADW 32
#define CSTR (PADH*PADW)            // 960 floats per channel
#define NIMG 32
#define NCH  128
#define HW   28
#define PBUF ((size_t)NIMG*NCH*CSTR)   // 3,932,160 floats per padded buffer
#define WREL (128*128*9)               // 147456 weights per tensor

// ---------------------------------------------------------------------------
// Quantize shift weights (sign * 2^round(log2|w|), zero below 0.005) and
// reorganize all 4 weight tensors to [cog32(32)][ci(128)][tap(9)][co4(4)] so
// the conv kernel stages one cog32 slice (4608 floats = 18 KB) into LDS.
__global__ __launch_bounds__(256) void prep_weights(
    const float* __restrict__ s1, const float* __restrict__ a1,
    const float* __restrict__ s2, const float* __restrict__ a2,
    float* __restrict__ dst) {
  int gid = blockIdx.x * 256 + threadIdx.x;          // 4*147456 threads
  int t = gid / WREL, r = gid % WREL;
  const float* src = (t == 0) ? s1 : (t == 1) ? a1 : (t == 2) ? s2 : a2;
  float v = src[r];
  if ((t & 1) == 0) {                                // t=0,2: shift weights
    float aw = fabsf(v);
    if (aw < 0.005f) {
      v = 0.0f;
    } else {
      int e; float m = frexpf(aw, &e);               // aw = m*2^e, m in [0.5,1)
      int k = (m >= 0.70710678f) ? e : e - 1;        // round(log2 aw)
      v = ldexpf(copysignf(1.0f, v), k);             // exact power of two
    }
  }
  // source layout [co][ci][3][3]
  int co = r / 1152, rem = r % 1152;
  int ci = rem / 9, tap = rem % 9;
  int cog = co >> 2, j = co & 3;
  dst[(size_t)t * WREL + (((cog * 128 + ci) * 9 + tap) << 2) + j] = v;
}

// ---------------------------------------------------------------------------
// x (compact NCHW) -> padded buffer with zero halos.  983040 float4 threads.
__global__ __launch_bounds__(256) void pad_copy(
    const float* __restrict__ x, float* __restrict__ o) {
  int idx = blockIdx.x * 256 + threadIdx.x;          // 983040 threads (PBUF/4)
  int f = idx * 4;
  int n = f / (NCH * CSTR);
  int c = (f / CSTR) % NCH;
  int o960 = f % CSTR;
  int r = o960 >> 5, col = o960 & 31;
  float4 out;
  float vals[4];
#pragma unroll
  for (int k = 0; k < 4; ++k) {
    int cc = col + k;
    bool inside = (r >= 1 && r <= HW && cc >= 1 && cc <= HW);
    vals[k] = inside ? x[(size_t)(n * NCH + c) * (HW * HW) + (r - 1) * HW + (cc - 1)]
                     : 0.0f;
  }
  out.x = vals[0]; out.y = vals[1]; out.z = vals[2]; out.w = vals[3];
  *(float4*)(o + f) = out;
}

// Zero the halo cells of a padded buffer (rows 0/29 fully, cols 0/29 of rows 1..28).
__global__ __launch_bounds__(256) void zero_halo(float* __restrict__ b) {
  int gid = blockIdx.x * 256 + threadIdx.x;          // 4096*120 threads
  int nc = gid / 120, i = gid % 120;
  float* p = b + (size_t)nc * CSTR;
  if (i < 64) {
    int row = (i < 32) ? 0 : (PADH - 1);
    p[row * PADW + (i & 31)] = 0.0f;
  } else {
    int i2 = i - 64;                                  // 56 entries: rows 1..28 x {0,29}
    int row = 1 + (i2 >> 1);
    int col = (i2 & 1) ? (HW + 1) : 0;
    p[row * PADW + col] = 0.0f;
  }
}

// ---------------------------------------------------------------------------
// 3x3 conv, stride 1. ADDER=0: out = sum w*in (shift conv, w pre-quantized).
// ADDER=1: out = -sum |in - w| (AdderNet).
// Block = one cog32 (4 output channels); 18 KB weight slice staged in LDS.
// Thread: 2 contiguous x positions x 4 output channels. Grid 1568 = 32 cog x 49.
// XCD-aware swizzle: XCD i gets ~6.1 contiguous chunks x all 32 cogs, so each
// input slab lives in exactly one XCD's L2 (working set ~2.5 MB < 4 MiB).
template<int ADDER>
__global__ __launch_bounds__(256, 8) void conv3x3(
    const float* __restrict__ in, const float* __restrict__ wr,
    float* __restrict__ out) {
  __shared__ float4 ws[1152];                         // 128 ci * 9 float4 = 18 KB
  int bid = blockIdx.x;                               // 0..1567, 1568 = 8*196
  int xcd = bid & 7, slot = bid >> 3;
  int v = xcd * 196 + slot;                           // bijective remap
  int cog = v & 31;
  int chunk = v >> 5;                                 // 0..48
  int tid = threadIdx.x;
  const float4* src4 = (const float4*)(wr + (size_t)cog * 4608);
#pragma unroll
  for (int k = 0; k < 5; ++k) {
    int i = k * 256 + tid;
    if (i < 1152) ws[i] = src4[i];
  }
  __syncthreads();

  int wi = chunk * 256 + tid;                         // 0..12543
  int xh = wi % 14;
  int r2 = wi / 14;
  int y = r2 % 28;
  int n = r2 / 28;
  int x0 = xh << 1;                                   // pixels x0, x0+1
  const float* ib = in + (size_t)n * NCH * CSTR + y * PADW + x0; // (ci=0, pad row y, col x0)
  float acc[4][2];
#pragma unroll
  for (int j = 0; j < 4; ++j) { acc[j][0] = 0.0f; acc[j][1] = 0.0f; }

  for (int ci = 0; ci < 128; ++ci) {
    float rv[3][4];                                   // padded cols x0..x0+3, rows y-1..y+1
#pragma unroll
    for (int ky = 0; ky < 3; ++ky) {
      float2 a = *(const float2*)(ib + ky * PADW);
      float2 b = *(const float2*)(ib + ky * PADW + 2);
      rv[ky][0] = a.x; rv[ky][1] = a.y; rv[ky][2] = b.x; rv[ky][3] = b.y;
    }
    const float4* wv = ws + ci * 9;
#pragma unroll
    for (int ky = 0; ky < 3; ++ky)
#pragma unroll
      for (int kx = 0; kx < 3; ++kx) {
        float4 wA = wv[ky * 3 + kx];                  // co 0..3 (LDS broadcast)
#pragma unroll
        for (int p = 0; p < 2; ++p) {
          float val = rv[ky][kx + p];
          if (ADDER) {
            acc[0][p] += fabsf(val - wA.x);
            acc[1][p] += fabsf(val - wA.y);
            acc[2][p] += fabsf(val - wA.z);
            acc[3][p] += fabsf(val - wA.w);
          } else {
            acc[0][p] = fmaf(val, wA.x, acc[0][p]);
            acc[1][p] = fmaf(val, wA.y, acc[1][p]);
            acc[2][p] = fmaf(val, wA.z, acc[2][p]);
            acc[3][p] = fmaf(val, wA.w, acc[3][p]);
          }
        }
      }
    ib += CSTR;
  }
  float* ob = out + ((size_t)(n * NCH + (cog << 2)) * PADH + (y + 1)) * PADW + (x0 + 1);
#pragma unroll
  for (int j = 0; j < 4; ++j) {
    ob[j * CSTR + 0] = ADDER ? -acc[j][0] : acc[j][0];
    ob[j * CSTR + 1] = ADDER ? -acc[j][1] : acc[j][1];
  }
}

// ---------------------------------------------------------------------------
// Batch stats per channel (training-mode BN), double accumulation to avoid
// E[x^2]-mean^2 cancellation. Deterministic tree reduction.
// Emits sb[c] = gamma*rstd, sb[128+c] = beta - mean*gamma*rstd.
__global__ __launch_bounds__(256) void bn_stats(
    const float* __restrict__ t, const float* __restrict__ gamma,
    const float* __restrict__ beta, float* __restrict__ sb) {
  int c = blockIdx.x;
  int tid = threadIdx.x;
  double s = 0.0, s2 = 0.0;
  for (int i = tid; i < NIMG * HW * HW; i += 256) {
    int n = i / (HW * HW);
    int rem = i % (HW * HW);
    int r = rem / HW, x = rem % HW;
    float v = t[((size_t)(n * NCH + c) * PADH + r + 1) * PADW + x + 1];
    s += v; s2 += (double)v * v;
  }
  __shared__ double sd[256], sq[256];
  sd[tid] = s; sq[tid] = s2;
  __syncthreads();
  for (int off = 128; off > 0; off >>= 1) {
    if (tid < off) { sd[tid] += sd[tid + off]; sq[tid] += sq[tid + off]; }
    __syncthreads();
  }
  if (tid == 0) {
    double cnt = (double)(NIMG * HW * HW);
    double mean = sd[0] / cnt;
    double var = sq[0] / cnt - mean * mean;
    double rstd = 1.0 / sqrt(var + 1e-5);
    double g = (double)gamma[c];
    sb[c] = (float)(g * rstd);
    sb[NCH + c] = (float)((double)beta[c] - mean * g * rstd);
  }
}

// BN apply + ReLU over the FULL padded grid (halos -> 0, which is exactly the
// zero-padding the next conv needs).
__global__ __launch_bounds__(256) void bn_apply_relu(
    const float* __restrict__ t, const float* __restrict__ sb,
    float* __restrict__ o) {
  int idx = blockIdx.x * 256 + threadIdx.x;          // 983040 threads (PBUF/4)
  int f = idx * 4;
  int c = (f / CSTR) % NCH;
  int o960 = f % CSTR;
  int r = o960 >> 5, col = o960 & 31;
  float4 v = *(const float4*)(t + f);
  float sc = sb[c], bi = sb[NCH + c];
  bool rin = (r >= 1 && r <= HW);
  float in0[4] = {v.x, v.y, v.z, v.w};
  float vals[4];
#pragma unroll
  for (int k = 0; k < 4; ++k) {
    int cc = col + k;
    float val = fmaxf(fmaf(in0[k], sc, bi), 0.0f);
    vals[k] = (rin && cc >= 1 && cc <= HW) ? val : 0.0f;
  }
  float4 out; out.x = vals[0]; out.y = vals[1]; out.z = vals[2]; out.w = vals[3];
  *(float4*)(o + f) = out;
}

// Final: out = relu(bn2(t5) + residual x), compact NCHW output.
__global__ __launch_bounds__(256) void final_kernel(
    const float* __restrict__ t5, const float* __restrict__ sb,
    const float* __restrict__ x, float* __restrict__ out) {
  int idx = blockIdx.x * 256 + threadIdx.x;          // 802816 float4 threads
  int f = idx * 4;
  int n = f / (NCH * HW * HW);
  int c = (f / (HW * HW)) % NCH;
  int o = f % (HW * HW);
  int y = o / HW, xc = o % HW;                        // xc % 4 == 0, same row
  const float* tp = t5 + ((size_t)(n * NCH + c) * PADH + y + 1) * PADW + xc + 1;
  float sc = sb[c], bi = sb[NCH + c];
  float4 xv = *(const float4*)(x + f);
  float4 ov;
  ov.x = fmaxf(fmaf(tp[0], sc, bi) + xv.x, 0.0f);
  ov.y = fmaxf(fmaf(tp[1], sc, bi) + xv.y, 0.0f);
  ov.z = fmaxf(fmaf(tp[2], sc, bi) + xv.z, 0.0f);
  ov.w = fmaxf(fmaf(tp[3], sc, bi) + xv.w, 0.0f);
  *(float4*)(out + f) = ov;
}

// ---------------------------------------------------------------------------
extern "C" void kernel_launch(void* const* d_in, const int* in_sizes, int n_in,
                              void* d_out, int out_size, void* d_ws, size_t ws_size,
                              hipStream_t stream) {
  const float* x   = (const float*)d_in[0];
  const float* ws1 = (const float*)d_in[1];
  const float* wa1 = (const float*)d_in[2];
  const float* g1  = (const float*)d_in[3];
  const float* b1  = (const float*)d_in[4];
  const float* ws2 = (const float*)d_in[5];
  const float* wa2 = (const float*)d_in[6];
  const float* g2  = (const float*)d_in[7];
  const float* b2  = (const float*)d_in[8];
  float* out = (float*)d_out;

  float* w  = (float*)d_ws;
  float* P0 = w;                    // x padded, later t3
  float* P1 = w + PBUF;             // t1, later t4
  float* P2 = w + 2 * PBUF;         // t2, later t5
  float* WQ = w + 3 * PBUF;         // 4 reorganized weight tensors
  float* Q1 = WQ;
  float* A1 = WQ + WREL;
  float* Q2 = WQ + 2 * (size_t)WREL;
  float* A2 = WQ + 3 * (size_t)WREL;
  float* SB1 = WQ + 4 * (size_t)WREL;   // scale/bias layer 1 (256 floats)
  float* SB2 = SB1 + 256;

  hipLaunchKernelGGL(prep_weights, dim3(2304), dim3(256), 0, stream, ws1, wa1, ws2, wa2, WQ);
  hipLaunchKernelGGL(pad_copy,     dim3(3840), dim3(256), 0, stream, x, P0);
  hipLaunchKernelGGL(zero_halo,    dim3(1920), dim3(256), 0, stream, P1);
  hipLaunchKernelGGL((conv3x3<0>), dim3(1568), dim3(256), 0, stream, P0, Q1, P1);  // t1 = shift1(x)
  hipLaunchKernelGGL((conv3x3<1>), dim3(1568), dim3(256), 0, stream, P1, A1, P2);  // t2 = adder1(t1)
  hipLaunchKernelGGL(bn_stats,     dim3(128),  dim3(256), 0, stream, P2, g1, b1, SB1);
  hipLaunchKernelGGL(bn_apply_relu,dim3(3840), dim3(256), 0, stream, P2, SB1, P0); // t3
  hipLaunchKernelGGL((conv3x3<0>), dim3(1568), dim3(256), 0, stream, P0, Q2, P1);  // t4 = shift2(t3)
  hipLaunchKernelGGL((conv3x3<1>), dim3(1568), dim3(256), 0, stream, P1, A2, P2);  // t5 = adder2(t4)
  hipLaunchKernelGGL(bn_stats,     dim3(128),  dim3(256), 0, stream, P2, g2, b2, SB2);
  hipLaunchKernelGGL(final_kernel, dim3(3136), dim3(256), 0, stream, P2, SB2, x, out);
}

// Round 5
// 895.086 us; speedup vs baseline: 2.3795x; 2.3795x over previous
//
#include <hip/hip_runtime.h>

// Padded layout for all intermediates: [N][C][30][32] floats.
// Row 0 / row 29 are y-halos; col 0 / col 29 are x-halos (zero); cols 30,31 pad.
// Element (y,x) of the logical 28x28 image lives at [y+1][x+1].
#define PADH 30
#define PADW 32
#define CSTR (PADH*PADW)            // 960 floats per channel
#define NIMG 32
#define NCH  128
#define HW   28
#define PBUF ((size_t)NIMG*NCH*CSTR)   // 3,932,160 floats per padded buffer
#define WREL (128*128*9)               // 147456 weights per tensor

// ---------------------------------------------------------------------------
// Quantize shift weights (sign * 2^round(log2|w|), zeroed below 0.005) and
// reorganize all 4 weight tensors to [cog(16)][ci(128)][tap(9)][co8] so the
// conv kernel stages one cog slice (9216 floats = 36 KB) into LDS.
__global__ __launch_bounds__(256) void prep_weights(
    const float* __restrict__ s1, const float* __restrict__ a1,
    const float* __restrict__ s2, const float* __restrict__ a2,
    float* __restrict__ dst) {
  int gid = blockIdx.x * 256 + threadIdx.x;          // 4*147456 threads
  int t = gid / WREL, r = gid % WREL;
  const float* src = (t == 0) ? s1 : (t == 1) ? a1 : (t == 2) ? s2 : a2;
  float v = src[r];
  if ((t & 1) == 0) {                                // t=0,2: shift weights
    float aw = fabsf(v);
    if (aw < 0.005f) {
      v = 0.0f;
    } else {
      int e; float m = frexpf(aw, &e);               // aw = m*2^e, m in [0.5,1)
      int k = (m >= 0.70710678f) ? e : e - 1;        // round(log2 aw)
      v = ldexpf(copysignf(1.0f, v), k);             // exact power of two
    }
  }
  // source layout [co][ci][3][3]
  int co = r / 1152, rem = r % 1152;
  int ci = rem / 9, tap = rem % 9;
  int cog = co >> 3, j = co & 7;
  dst[(size_t)t * WREL + (((cog * 128 + ci) * 9 + tap) << 3) + j] = v;
}

// ---------------------------------------------------------------------------
// x (compact NCHW) -> padded buffer with zero halos.  983040 float4 threads.
__global__ __launch_bounds__(256) void pad_copy(
    const float* __restrict__ x, float* __restrict__ o) {
  int idx = blockIdx.x * 256 + threadIdx.x;          // 983040 threads (PBUF/4)
  int f = idx * 4;
  int n = f / (NCH * CSTR);
  int c = (f / CSTR) % NCH;
  int o960 = f % CSTR;
  int r = o960 >> 5, col = o960 & 31;
  float4 out;
  float vals[4];
#pragma unroll
  for (int k = 0; k < 4; ++k) {
    int cc = col + k;
    bool inside = (r >= 1 && r <= HW && cc >= 1 && cc <= HW);
    vals[k] = inside ? x[(size_t)(n * NCH + c) * (HW * HW) + (r - 1) * HW + (cc - 1)]
                     : 0.0f;
  }
  out.x = vals[0]; out.y = vals[1]; out.z = vals[2]; out.w = vals[3];
  *(float4*)(o + f) = out;
}

// Zero the halo cells of a padded buffer (rows 0/29 fully, cols 0/29 of rows 1..28).
__global__ __launch_bounds__(256) void zero_halo(float* __restrict__ b) {
  int gid = blockIdx.x * 256 + threadIdx.x;          // 4096*120 threads
  int nc = gid / 120, i = gid % 120;
  float* p = b + (size_t)nc * CSTR;
  if (i < 64) {
    int row = (i < 32) ? 0 : (PADH - 1);
    p[row * PADW + (i & 31)] = 0.0f;
  } else {
    int i2 = i - 64;                                  // 56 entries: rows 1..28 x {0,29}
    int row = 1 + (i2 >> 1);
    int col = (i2 & 1) ? (HW + 1) : 0;
    p[row * PADW + col] = 0.0f;
  }
}

// ---------------------------------------------------------------------------
// Load one ci's 3 input rows (4 padded cols) into registers. 8B-aligned float2s.
__device__ __forceinline__ void load_rows(const float* __restrict__ p,
                                          float r[3][4]) {
#pragma unroll
  for (int ky = 0; ky < 3; ++ky) {
    float2 a = *(const float2*)(p + ky * PADW);
    float2 b = *(const float2*)(p + ky * PADW + 2);
    r[ky][0] = a.x; r[ky][1] = a.y; r[ky][2] = b.x; r[ky][3] = b.y;
  }
}

template<int ADDER>
__device__ __forceinline__ void compute_ci(const float r[3][4],
                                           const float4* __restrict__ wv,
                                           float acc[8][2]) {
#pragma unroll
  for (int ky = 0; ky < 3; ++ky)
#pragma unroll
    for (int kx = 0; kx < 3; ++kx) {
      float4 wA = wv[(ky * 3 + kx) * 2];              // co 0..3 (LDS broadcast)
      float4 wB = wv[(ky * 3 + kx) * 2 + 1];          // co 4..7
#pragma unroll
      for (int p = 0; p < 2; ++p) {
        float v = r[ky][kx + p];
        if (ADDER) {
          acc[0][p] += fabsf(v - wA.x);
          acc[1][p] += fabsf(v - wA.y);
          acc[2][p] += fabsf(v - wA.z);
          acc[3][p] += fabsf(v - wA.w);
          acc[4][p] += fabsf(v - wB.x);
          acc[5][p] += fabsf(v - wB.y);
          acc[6][p] += fabsf(v - wB.z);
          acc[7][p] += fabsf(v - wB.w);
        } else {
          acc[0][p] = fmaf(v, wA.x, acc[0][p]);
          acc[1][p] = fmaf(v, wA.y, acc[1][p]);
          acc[2][p] = fmaf(v, wA.z, acc[2][p]);
          acc[3][p] = fmaf(v, wA.w, acc[3][p]);
          acc[4][p] = fmaf(v, wB.x, acc[4][p]);
          acc[5][p] = fmaf(v, wB.y, acc[5][p]);
          acc[6][p] = fmaf(v, wB.z, acc[6][p]);
          acc[7][p] = fmaf(v, wB.w, acc[7][p]);
        }
      }
    }
}

// 3x3 conv, stride 1. ADDER=0: out = sum w*in (shift conv, w pre-quantized).
// ADDER=1: out = -sum |in - w| (AdderNet).
// Block = one cog (8 output channels); 36 KB weight slice staged in LDS.
// Thread: 2 contiguous x positions x 8 output channels. Grid 784 = 16 cog x 49.
// XCD-aware swizzle (784 = 8*98, bijective): each XCD owns ~6 consecutive
// spatial chunks x all 16 cogs -> input slab stays in one XCD's L2 (~3 MB).
// ci-loop is 2-deep software-pipelined (ping-pong row regs) to hide L2 latency.
template<int ADDER>
__global__ __launch_bounds__(256, 4) void conv3x3(
    const float* __restrict__ in, const float* __restrict__ wr,
    float* __restrict__ out) {
  __shared__ float4 ws[2304];                         // 128 ci * 18 float4 = 36 KB
  int bid = blockIdx.x;
  int v = (bid & 7) * 98 + (bid >> 3);                // XCD-contiguous remap
  int cog = v & 15;
  int chunk = v >> 4;                                 // 0..48
  int tid = threadIdx.x;
  const float4* src4 = (const float4*)(wr + (size_t)cog * 9216);
#pragma unroll
  for (int k = 0; k < 9; ++k) ws[k * 256 + tid] = src4[k * 256 + tid];
  __syncthreads();

  int wi = chunk * 256 + tid;                         // 0..12543
  int xh = wi % 14;
  int r2 = wi / 14;
  int y = r2 % 28;
  int n = r2 / 28;
  int x0 = xh << 1;                                   // pixels x0, x0+1
  const float* ib = in + (size_t)n * NCH * CSTR + y * PADW + x0; // padded (y-1..y+1, x0-1..x0+2)
  float acc[8][2];
#pragma unroll
  for (int j = 0; j < 8; ++j) { acc[j][0] = 0.0f; acc[j][1] = 0.0f; }

  float ra[3][4], rb[3][4];
  load_rows(ib, ra);                                  // ci = 0
  for (int ci = 0; ci < 128; ci += 2) {
    load_rows(ib + CSTR, rb);                         // prefetch ci+1
    compute_ci<ADDER>(ra, ws + ci * 18, acc);         // compute ci (waits ra only)
    if (ci + 2 < 128) load_rows(ib + 2 * CSTR, ra);   // prefetch ci+2
    compute_ci<ADDER>(rb, ws + (ci + 1) * 18, acc);   // compute ci+1
    ib += 2 * CSTR;
  }

  float* ob = out + ((size_t)(n * NCH + (cog << 3)) * PADH + (y + 1)) * PADW + (x0 + 1);
#pragma unroll
  for (int j = 0; j < 8; ++j) {
    ob[j * CSTR + 0] = ADDER ? -acc[j][0] : acc[j][0];
    ob[j * CSTR + 1] = ADDER ? -acc[j][1] : acc[j][1];
  }
}

// ---------------------------------------------------------------------------
// Batch stats per channel (training-mode BN), double accumulation to avoid
// E[x^2]-mean^2 cancellation. Deterministic tree reduction.
// Emits sb[c] = gamma*rstd, sb[128+c] = beta - mean*gamma*rstd.
__global__ __launch_bounds__(256) void bn_stats(
    const float* __restrict__ t, const float* __restrict__ gamma,
    const float* __restrict__ beta, float* __restrict__ sb) {
  int c = blockIdx.x;
  int tid = threadIdx.x;
  double s = 0.0, s2 = 0.0;
  for (int i = tid; i < NIMG * HW * HW; i += 256) {
    int n = i / (HW * HW);
    int rem = i % (HW * HW);
    int r = rem / HW, x = rem % HW;
    float v = t[((size_t)(n * NCH + c) * PADH + r + 1) * PADW + x + 1];
    s += v; s2 += (double)v * v;
  }
  __shared__ double sd[256], sq[256];
  sd[tid] = s; sq[tid] = s2;
  __syncthreads();
  for (int off = 128; off > 0; off >>= 1) {
    if (tid < off) { sd[tid] += sd[tid + off]; sq[tid] += sq[tid + off]; }
    __syncthreads();
  }
  if (tid == 0) {
    double cnt = (double)(NIMG * HW * HW);
    double mean = sd[0] / cnt;
    double var = sq[0] / cnt - mean * mean;
    double rstd = 1.0 / sqrt(var + 1e-5);
    double g = (double)gamma[c];
    sb[c] = (float)(g * rstd);
    sb[NCH + c] = (float)((double)beta[c] - mean * g * rstd);
  }
}

// BN apply + ReLU over the FULL padded grid (halos -> 0, which is exactly the
// zero-padding the next conv needs).
__global__ __launch_bounds__(256) void bn_apply_relu(
    const float* __restrict__ t, const float* __restrict__ sb,
    float* __restrict__ o) {
  int idx = blockIdx.x * 256 + threadIdx.x;          // 983040 threads (PBUF/4)
  int f = idx * 4;
  int c = (f / CSTR) % NCH;
  int o960 = f % CSTR;
  int r = o960 >> 5, col = o960 & 31;
  float4 v = *(const float4*)(t + f);
  float sc = sb[c], bi = sb[NCH + c];
  bool rin = (r >= 1 && r <= HW);
  float in0[4] = {v.x, v.y, v.z, v.w};
  float vals[4];
#pragma unroll
  for (int k = 0; k < 4; ++k) {
    int cc = col + k;
    float val = fmaxf(fmaf(in0[k], sc, bi), 0.0f);
    vals[k] = (rin && cc >= 1 && cc <= HW) ? val : 0.0f;
  }
  float4 out; out.x = vals[0]; out.y = vals[1]; out.z = vals[2]; out.w = vals[3];
  *(float4*)(o + f) = out;
}

// Final: out = relu(bn2(t5) + residual x), compact NCHW output.
__global__ __launch_bounds__(256) void final_kernel(
    const float* __restrict__ t5, const float* __restrict__ sb,
    const float* __restrict__ x, float* __restrict__ out) {
  int idx = blockIdx.x * 256 + threadIdx.x;          // 802816 float4 threads
  int f = idx * 4;
  int n = f / (NCH * HW * HW);
  int c = (f / (HW * HW)) % NCH;
  int o = f % (HW * HW);
  int y = o / HW, xc = o % HW;                        // xc % 4 == 0, same row
  const float* tp = t5 + ((size_t)(n * NCH + c) * PADH + y + 1) * PADW + xc + 1;
  float sc = sb[c], bi = sb[NCH + c];
  float4 xv = *(const float4*)(x + f);
  float4 ov;
  ov.x = fmaxf(fmaf(tp[0], sc, bi) + xv.x, 0.0f);
  ov.y = fmaxf(fmaf(tp[1], sc, bi) + xv.y, 0.0f);
  ov.z = fmaxf(fmaf(tp[2], sc, bi) + xv.z, 0.0f);
  ov.w = fmaxf(fmaf(tp[3], sc, bi) + xv.w, 0.0f);
  *(float4*)(out + f) = ov;
}

// ---------------------------------------------------------------------------
extern "C" void kernel_launch(void* const* d_in, const int* in_sizes, int n_in,
                              void* d_out, int out_size, void* d_ws, size_t ws_size,
                              hipStream_t stream) {
  const float* x   = (const float*)d_in[0];
  const float* ws1 = (const float*)d_in[1];
  const float* wa1 = (const float*)d_in[2];
  const float* g1  = (const float*)d_in[3];
  const float* b1  = (const float*)d_in[4];
  const float* ws2 = (const float*)d_in[5];
  const float* wa2 = (const float*)d_in[6];
  const float* g2  = (const float*)d_in[7];
  const float* b2  = (const float*)d_in[8];
  float* out = (float*)d_out;

  float* w  = (float*)d_ws;
  float* P0 = w;                    // x padded, later t3
  float* P1 = w + PBUF;             // t1, later t4
  float* P2 = w + 2 * PBUF;         // t2, later t5
  float* WQ = w + 3 * PBUF;         // 4 reorganized weight tensors
  float* Q1 = WQ;
  float* A1 = WQ + WREL;
  float* Q2 = WQ + 2 * (size_t)WREL;
  float* A2 = WQ + 3 * (size_t)WREL;
  float* SB1 = WQ + 4 * (size_t)WREL;   // scale/bias layer 1 (256 floats)
  float* SB2 = SB1 + 256;

  hipLaunchKernelGGL(prep_weights, dim3(2304), dim3(256), 0, stream, ws1, wa1, ws2, wa2, WQ);
  hipLaunchKernelGGL(pad_copy,     dim3(3840), dim3(256), 0, stream, x, P0);
  hipLaunchKernelGGL(zero_halo,    dim3(1920), dim3(256), 0, stream, P1);
  hipLaunchKernelGGL((conv3x3<0>), dim3(784),  dim3(256), 0, stream, P0, Q1, P1);  // t1 = shift1(x)
  hipLaunchKernelGGL((conv3x3<1>), dim3(784),  dim3(256), 0, stream, P1, A1, P2);  // t2 = adder1(t1)
  hipLaunchKernelGGL(bn_stats,     dim3(128),  dim3(256), 0, stream, P2, g1, b1, SB1);
  hipLaunchKernelGGL(bn_apply_relu,dim3(3840), dim3(256), 0, stream, P2, SB1, P0); // t3
  hipLaunchKernelGGL((conv3x3<0>), dim3(784),  dim3(256), 0, stream, P0, Q2, P1);  // t4 = shift2(t3)
  hipLaunchKernelGGL((conv3x3<1>), dim3(784),  dim3(256), 0, stream, P1, A2, P2);  // t5 = adder2(t4)
  hipLaunchKernelGGL(bn_stats,     dim3(128),  dim3(256), 0, stream, P2, g2, b2, SB2);
  hipLaunchKernelGGL(final_kernel, dim3(3136), dim3(256), 0, stream, P2, SB2, x, out);
}